// Round 4
// baseline (284.787 us; speedup 1.0000x reference)
//
#include <hip/hip_runtime.h>
#include <cstdint>

using u16 = unsigned short;
typedef short bf16x8 __attribute__((ext_vector_type(8)));
typedef float f32x4 __attribute__((ext_vector_type(4)));

__device__ __forceinline__ float bf2f(u16 h) {
    union { unsigned u; float f; } x;
    x.u = ((unsigned)h) << 16;
    return x.f;
}
__device__ __forceinline__ u16 f2bf(float f) {
    union { float f; unsigned u; } x;
    x.f = f;
    unsigned r = x.u + 0x7fffu + ((x.u >> 16) & 1u);
    return (u16)(r >> 16);
}

#define N1 8192
#define N2 2048
#define C2 256

// ---------------------------------------------------------------------------
// fused prep: w0/w1 fp32->bf16, xyz2 pack to float4(-2x,-2y,-2z,|p|^2),
// stats zero. One dispatch replaces 2 cvt kernels + hipMemsetAsync.
// Note -2*x is EXACT in fp32 and rounding commutes with *2, so the scan's
// sq reconstruction below is bit-identical to the reference formula.
// ---------------------------------------------------------------------------
__global__ __launch_bounds__(256) void prep_misc(const float* __restrict__ w0,
                                                 const float* __restrict__ w1,
                                                 const float* __restrict__ xyz2,
                                                 u16* __restrict__ w0b,
                                                 u16* __restrict__ w1b,
                                                 float4* __restrict__ P2P,
                                                 float* __restrict__ stats) {
    int bid = blockIdx.x, tid = threadIdx.x;
    if (bid < 384) {
        int i = bid * 256 + tid;
        w0b[i] = f2bf(w0[i]);
    } else if (bid < 512) {
        int i = (bid - 384) * 256 + tid;
        w1b[i] = f2bf(w1[i]);
    } else if (bid < 576) {
        int i = (bid - 512) * 256 + tid;  // 16384 points
        float x = xyz2[i * 3 + 0], y = xyz2[i * 3 + 1], z = xyz2[i * 3 + 2];
        float nsq = __fadd_rn(__fadd_rn(__fmul_rn(x, x), __fmul_rn(y, y)), __fmul_rn(z, z));
        P2P[i] = make_float4(-2.0f * x, -2.0f * y, -2.0f * z, nsq);
    } else {
        for (int i = tid; i < 768; i += 256) stats[i] = 0.0f;
    }
}

// ---------------------------------------------------------------------------
// [B][C][N] fp32 -> [B][N][dst_stride] bf16 transpose (col offset col_off)
// ---------------------------------------------------------------------------
__global__ __launch_bounds__(256) void transpose_to_bf16(const float* __restrict__ src,
                                                         u16* __restrict__ dst,
                                                         int C, int N, int dst_stride,
                                                         int col_off) {
    __shared__ float tile[32][33];
    int b = blockIdx.z;
    int n0 = blockIdx.x * 32, c0 = blockIdx.y * 32;
    int tx = threadIdx.x & 31, ty = threadIdx.x >> 5;  // 32 x 8
    const float* s = src + (long)b * C * N;
#pragma unroll
    for (int i = 0; i < 4; i++) {
        int c = ty + i * 8;
        tile[c][tx] = s[(long)(c0 + c) * N + n0 + tx];
    }
    __syncthreads();
    u16* d = dst + (long)b * N * dst_stride;
#pragma unroll
    for (int i = 0; i < 4; i++) {
        int n = ty + i * 8;
        d[(long)(n0 + n) * dst_stride + col_off + c0 + tx] = f2bf(tile[tx][n]);
    }
}

// ---------------------------------------------------------------------------
// kNN(3) + inverse-distance interpolation, v3 (R4).
// R3 was VALU-inst-bound: ~34 VALU/iter (cndmask cascade + LDS addressing),
// 16 waves/CU. v3: candidates via wave-uniform s_load from packed P2P
// (no LDS staging, no VALU address math), sorted-insert min/max network
// (~20 VALU/iter), block=512 (8 waves = 8 partitions x 256 candidates),
// grid (128,8) -> 4 blocks/CU = 32 waves/CU (occupancy 2x).
// Exact reference rounding: sq = (psq + w) + ((-2x*px + -2y*py) + -2z*pz)
// is bit-identical to ref ((psq+|p2|^2) - 2*dot) since *2 is exact.
// ---------------------------------------------------------------------------
__global__ __launch_bounds__(512) void knn_interp(const float* __restrict__ xyz1,
                                                  const float4* __restrict__ P2P,  // [B][N2]
                                                  const u16* __restrict__ P2T,     // [B][N2][C2]
                                                  u16* __restrict__ X) {           // [B*N1][384]
    __shared__ float m_d[8][64][3];     // per-part top-3 (squared dist)
    __shared__ int   m_i[8][64][3];
    __shared__ int   s_idx[64][3];
    __shared__ float s_w[64][3];
    int b = blockIdx.y;
    int n0 = blockIdx.x * 64;
    int tid = threadIdx.x;
    int ql = tid & 63;                                        // query lane
    int part = __builtin_amdgcn_readfirstlane(tid >> 6);      // wave id 0..7 (uniform)

    int n = n0 + ql;
    float px = xyz1[((long)b * N1 + n) * 3 + 0];
    float py = xyz1[((long)b * N1 + n) * 3 + 1];
    float pz = xyz1[((long)b * N1 + n) * 3 + 2];
    float psq = __fadd_rn(__fadd_rn(__fmul_rn(px, px), __fmul_rn(py, py)), __fmul_rn(pz, pz));

    // scan 256 candidates; pointer is wave-uniform -> s_load path
    const float4* __restrict__ pp = P2P + (long)b * N2 + part * (N2 / 8);
    int jbeg = part * (N2 / 8);
    float b0 = 1e30f, b1 = 1e30f, b2 = 1e30f;
    int i0 = 0, i1 = 0, i2 = 0;
#pragma unroll 4
    for (int jj = 0; jj < N2 / 8; jj++) {
        float4 p = pp[jj];
        float u = __fadd_rn(__fadd_rn(__fmul_rn(p.x, px), __fmul_rn(p.y, py)),
                            __fmul_rn(p.z, pz));
        float sq = __fadd_rn(__fadd_rn(psq, p.w), u);
        int j = jbeg + jj;
        // sorted insert, strict < (ties keep earlier/lower index):
        bool c0 = sq < b0, c1 = sq < b1, c2 = sq < b2;
        float t1 = c0 ? b0 : sq;  int ti1 = c0 ? i0 : j;
        b0 = c0 ? sq : b0;        i0 = c0 ? j : i0;
        float t2 = c1 ? b1 : t1;  int ti2 = c1 ? i1 : ti1;
        b1 = c1 ? t1 : b1;        i1 = c1 ? ti1 : i1;
        b2 = c2 ? t2 : b2;        i2 = c2 ? ti2 : i2;
    }
    m_d[part][ql][0] = b0; m_d[part][ql][1] = b1; m_d[part][ql][2] = b2;
    m_i[part][ql][0] = i0; m_i[part][ql][1] = i1; m_i[part][ql][2] = i2;
    __syncthreads();

    // merge 8x3 partials -> top-3, lexicographic (sq, idx). Parts scan
    // disjoint ascending ranges so all 24 entries are distinct candidates.
    if (tid < 64) {
        float c0 = 1e30f, c1 = 1e30f, c2 = 1e30f;
        int a0 = 0x7fffffff, a1 = 0x7fffffff, a2 = 0x7fffffff;
#pragma unroll
        for (int pp2 = 0; pp2 < 8; pp2++) {
#pragma unroll
            for (int k = 0; k < 3; k++) {
                float d = m_d[pp2][tid][k];
                int ix = m_i[pp2][tid][k];
                if (d < c2 || (d == c2 && ix < a2)) {
                    if (d < c1 || (d == c1 && ix < a1)) {
                        c2 = c1; a2 = a1;
                        if (d < c0 || (d == c0 && ix < a0)) { c1 = c0; a1 = a0; c0 = d; a0 = ix; }
                        else                                { c1 = d; a1 = ix; }
                    } else { c2 = d; a2 = ix; }
                }
            }
        }
        // exact reference math for the winners: d = sqrt(max(sq,0)), clamp 1e-10
        float e0 = sqrtf(fmaxf(c0, 0.0f));
        float e1 = sqrtf(fmaxf(c1, 0.0f));
        float e2 = sqrtf(fmaxf(c2, 0.0f));
        float kd0 = fmaxf(e0, 1e-10f), kd1 = fmaxf(e1, 1e-10f), kd2 = fmaxf(e2, 1e-10f);
        float w0 = __fdiv_rn(1.0f, kd0), w1 = __fdiv_rn(1.0f, kd1), w2 = __fdiv_rn(1.0f, kd2);
        float wsum = __fadd_rn(__fadd_rn(w0, w1), w2);
        s_idx[tid][0] = a0; s_idx[tid][1] = a1; s_idx[tid][2] = a2;
        s_w[tid][0] = __fdiv_rn(w0, wsum);
        s_w[tid][1] = __fdiv_rn(w1, wsum);
        s_w[tid][2] = __fdiv_rn(w2, wsum);
    }
    __syncthreads();

    // gather: wave w handles queries p = w, w+8, ...; lane l covers channels
    // [4l, 4l+4) as ushort4 (8 B/lane, coalesced 512 B/wave).
    int l = tid & 63;
    const u16* base = P2T + (long)b * N2 * C2;
    for (int p = part; p < 64; p += 8) {
        int j0 = s_idx[p][0], j1 = s_idx[p][1], j2 = s_idx[p][2];  // broadcast
        float f0 = s_w[p][0], f1 = s_w[p][1], f2 = s_w[p][2];
        ushort4 r0 = *(const ushort4*)&base[(long)j0 * C2 + l * 4];
        ushort4 r1 = *(const ushort4*)&base[(long)j1 * C2 + l * 4];
        ushort4 r2 = *(const ushort4*)&base[(long)j2 * C2 + l * 4];
        ushort4 o;
        o.x = f2bf(__fadd_rn(__fadd_rn(__fmul_rn(bf2f(r0.x), f0), __fmul_rn(bf2f(r1.x), f1)),
                             __fmul_rn(bf2f(r2.x), f2)));
        o.y = f2bf(__fadd_rn(__fadd_rn(__fmul_rn(bf2f(r0.y), f0), __fmul_rn(bf2f(r1.y), f1)),
                             __fmul_rn(bf2f(r2.y), f2)));
        o.z = f2bf(__fadd_rn(__fadd_rn(__fmul_rn(bf2f(r0.z), f0), __fmul_rn(bf2f(r1.z), f1)),
                             __fmul_rn(bf2f(r2.z), f2)));
        o.w = f2bf(__fadd_rn(__fadd_rn(__fmul_rn(bf2f(r0.w), f0), __fmul_rn(bf2f(r1.w), f1)),
                             __fmul_rn(bf2f(r2.w), f2)));
        *(ushort4*)&X[(long)(b * N1 + n0 + p) * 384 + 128 + l * 4] = o;
    }
}

// ---------------------------------------------------------------------------
// bf16 MFMA GEMM: Y[M][Ntot] = A[M][KDIM] * Bw[Ntot][KDIM]^T + bias
// Block tile 128x128, 4 waves each 64x64 (4x4 of 16x16x32 MFMA).
// Optional fused BN+ReLU on the input (per-k scale/shift from global stats).
// Epilogue accumulates per-output-channel sum / sumsq via atomics.
// ---------------------------------------------------------------------------
template <int KDIM, bool BN_IN, bool OUT_BF16>
__global__ __launch_bounds__(256) void gemm_bn(const u16* __restrict__ A,
                                               const u16* __restrict__ Bw,
                                               const float* __restrict__ bias,
                                               const float* __restrict__ g_in_sum,
                                               const float* __restrict__ g_in_ssq,
                                               const float* __restrict__ gamma_in,
                                               const float* __restrict__ beta_in,
                                               void* __restrict__ Yout, int Ntot,
                                               float* __restrict__ g_out_sum,
                                               float* __restrict__ g_out_ssq) {
    __shared__ __align__(16) u16 Al[128 * 40];  // +8 pad: conflict-free ds_read_b128
    __shared__ __align__(16) u16 Bl[128 * 40];
    __shared__ float s_stats[256];
    __shared__ float s_scale[BN_IN ? KDIM : 2];
    __shared__ float s_shift[BN_IN ? KDIM : 2];

    int tid = threadIdx.x;
    long s0 = (long)blockIdx.x * 128;
    int o0 = blockIdx.y * 128;

    s_stats[tid < 256 ? tid : 0] = 0.0f;
    if constexpr (BN_IN) {
        for (int k = tid; k < KDIM; k += 256) {
            float mu = g_in_sum[k] * (1.0f / 65536.0f);
            float var = g_in_ssq[k] * (1.0f / 65536.0f) - mu * mu;
            float rs = rsqrtf(var + 1e-5f);
            float sc = gamma_in[k] * rs;
            s_scale[k] = sc;
            s_shift[k] = beta_in[k] - mu * sc;
        }
    }
    int wid = tid >> 6, lane = tid & 63;
    int wm = wid >> 1, wn = wid & 1;
    int q = lane >> 4, l16 = lane & 15;

    f32x4 acc[4][4];
#pragma unroll
    for (int mi = 0; mi < 4; mi++)
#pragma unroll
        for (int ni = 0; ni < 4; ni++) acc[mi][ni] = (f32x4){0.f, 0.f, 0.f, 0.f};
    __syncthreads();

    for (int kt = 0; kt < KDIM; kt += 32) {
#pragma unroll
        for (int cc = 0; cc < 2; cc++) {
            int ci = tid + cc * 256;
            int row = ci >> 2;
            int kc = (ci & 3) << 3;
            union { uint4 u; u16 h[8]; } va;
            va.u = *(const uint4*)(A + (s0 + row) * KDIM + kt + kc);
            if constexpr (BN_IN) {
#pragma unroll
                for (int j = 0; j < 8; j++) {
                    float f = bf2f(va.h[j]);
                    f = fmaxf(fmaf(f, s_scale[kt + kc + j], s_shift[kt + kc + j]), 0.0f);
                    va.h[j] = f2bf(f);
                }
            }
            *(uint4*)&Al[row * 40 + kc] = va.u;
            *(uint4*)&Bl[row * 40 + kc] = *(const uint4*)(Bw + (long)(o0 + row) * KDIM + kt + kc);
        }
        __syncthreads();
        bf16x8 af[4], bfr[4];
#pragma unroll
        for (int mi = 0; mi < 4; mi++)
            af[mi] = *(const bf16x8*)&Al[(wm * 64 + mi * 16 + l16) * 40 + q * 8];
#pragma unroll
        for (int ni = 0; ni < 4; ni++)
            bfr[ni] = *(const bf16x8*)&Bl[(wn * 64 + ni * 16 + l16) * 40 + q * 8];
#pragma unroll
        for (int mi = 0; mi < 4; mi++)
#pragma unroll
            for (int ni = 0; ni < 4; ni++)
                acc[mi][ni] = __builtin_amdgcn_mfma_f32_16x16x32_bf16(af[mi], bfr[ni],
                                                                      acc[mi][ni], 0, 0, 0);
        __syncthreads();
    }

    // epilogue: bias add, store, per-channel sum/sumsq
#pragma unroll
    for (int ni = 0; ni < 4; ni++) {
        int coll = wn * 64 + ni * 16 + l16;
        int col = o0 + coll;
        float bz = bias[col];
        float s1 = 0.0f, s2 = 0.0f;
#pragma unroll
        for (int mi = 0; mi < 4; mi++) {
#pragma unroll
            for (int r = 0; r < 4; r++) {
                float v = acc[mi][ni][r] + bz;
                s1 += v;
                s2 += v * v;
                long row = s0 + wm * 64 + mi * 16 + q * 4 + r;
                if constexpr (OUT_BF16)
                    ((u16*)Yout)[row * Ntot + col] = f2bf(v);
                else
                    ((float*)Yout)[row * Ntot + col] = v;
            }
        }
        s1 += __shfl_xor(s1, 16, 64);
        s1 += __shfl_xor(s1, 32, 64);
        s2 += __shfl_xor(s2, 16, 64);
        s2 += __shfl_xor(s2, 32, 64);
        if (q == 0) {
            atomicAdd(&s_stats[coll], s1);
            atomicAdd(&s_stats[128 + coll], s2);
        }
    }
    __syncthreads();
    if (tid < 128) {
        atomicAdd(&g_out_sum[o0 + tid], s_stats[tid]);
        atomicAdd(&g_out_ssq[o0 + tid], s_stats[128 + tid]);
    }
}

// ---------------------------------------------------------------------------
// final BN+ReLU + transpose to [B][128][N1] fp32 (Y1 now bf16, 16B reads)
// ---------------------------------------------------------------------------
__global__ __launch_bounds__(256) void finalize_k(const u16* __restrict__ Y1,  // [M][128] bf16
                                                  const float* __restrict__ g_sum,
                                                  const float* __restrict__ g_ssq,
                                                  const float* __restrict__ gamma,
                                                  const float* __restrict__ beta,
                                                  float* __restrict__ out) {
    __shared__ float s_scale[128], s_shift[128];
    int tid = threadIdx.x;
    if (tid < 128) {
        float mu = g_sum[tid] * (1.0f / 65536.0f);
        float var = g_ssq[tid] * (1.0f / 65536.0f) - mu * mu;
        float rs = rsqrtf(var + 1e-5f);
        float sc = gamma[tid] * rs;
        s_scale[tid] = sc;
        s_shift[tid] = beta[tid] - mu * sc;
    }
    __syncthreads();
    long s = (long)blockIdx.x * 256 + tid;
    int b = (int)(s >> 13);
    int n = (int)(s & 8191);
    const u16* yrow = Y1 + s * 128;
    float* obase = out + (long)b * 128 * 8192 + n;
#pragma unroll
    for (int oc = 0; oc < 128; oc += 8) {
        union { uint4 u; u16 h[8]; } va;
        va.u = *(const uint4*)&yrow[oc];
#pragma unroll
        for (int k = 0; k < 8; k++) {
            int o = oc + k;
            float v = fmaxf(fmaf(bf2f(va.h[k]), s_scale[o], s_shift[o]), 0.0f);
            obase[(long)o * 8192] = v;
        }
    }
}

// ---------------------------------------------------------------------------
// launch
// ---------------------------------------------------------------------------
extern "C" void kernel_launch(void* const* d_in, const int* in_sizes, int n_in,
                              void* d_out, int out_size, void* d_ws, size_t ws_size,
                              hipStream_t stream) {
    const float* xyz1    = (const float*)d_in[0];
    const float* xyz2    = (const float*)d_in[1];
    const float* points1 = (const float*)d_in[2];
    const float* points2 = (const float*)d_in[3];
    const float* w0 = (const float*)d_in[4];
    const float* b0 = (const float*)d_in[5];
    const float* gamma0 = (const float*)d_in[6];
    const float* beta0 = (const float*)d_in[7];
    const float* w1 = (const float*)d_in[8];
    const float* b1 = (const float*)d_in[9];
    const float* gamma1 = (const float*)d_in[10];
    const float* beta1 = (const float*)d_in[11];
    float* out = (float*)d_out;

    char* ws = (char*)d_ws;
    // ws layout (all 256B aligned). P2P shares space freed before gemm1 runs.
    u16* X      = (u16*)(ws + 0);            // 65536 x 384 bf16 = 50,331,648
    u16* P2T    = (u16*)(ws + 50331648);     // 8 x 2048 x 256 bf16 = 8,388,608
    u16* w0b    = (u16*)(ws + 58720256);     // 256 x 384 bf16 = 196,608
    u16* w1b    = (u16*)(ws + 58916864);     // 128 x 256 bf16 = 65,536
    u16* Y0     = (u16*)(ws + 58982400);     // 65536 x 256 bf16 = 33,554,432
    float4* P2P = (float4*)(ws + 92536832);  // 16384 x 16 = 262,144
    u16* Y1b    = (u16*)(ws + 92798976);     // 65536 x 128 bf16 = 16,777,216
    float* stats = (float*)(ws + 126091264); // 768 floats
    if (ws_size < 126094336) return;  // insufficient scratch -> visible failure
    float* gsum0 = stats;
    float* gss0  = stats + 256;
    float* gsum1 = stats + 512;
    float* gss1  = stats + 640;

    prep_misc<<<577, 256, 0, stream>>>(w0, w1, xyz2, w0b, w1b, P2P, stats);
    transpose_to_bf16<<<dim3(256, 4, 8), 256, 0, stream>>>(points1, X, 128, 8192, 384, 0);
    transpose_to_bf16<<<dim3(64, 8, 8), 256, 0, stream>>>(points2, P2T, 256, 2048, 256, 0);
    knn_interp<<<dim3(128, 8), 512, 0, stream>>>(xyz1, P2P, P2T, X);
    gemm_bn<384, false, true><<<dim3(512, 2), 256, 0, stream>>>(
        X, w0b, b0, nullptr, nullptr, nullptr, nullptr, Y0, 256, gsum0, gss0);
    gemm_bn<256, true, true><<<dim3(512, 1), 256, 0, stream>>>(
        Y0, w1b, b1, gsum0, gss0, gamma0, beta0, Y1b, 128, gsum1, gss1);
    finalize_k<<<256, 256, 0, stream>>>(Y1b, gsum1, gss1, gamma1, beta1, out);
}

// Round 5
// 277.631 us; speedup vs baseline: 1.0258x; 1.0258x over previous
//
#include <hip/hip_runtime.h>
#include <cstdint>

using u16 = unsigned short;
typedef short bf16x8 __attribute__((ext_vector_type(8)));
typedef float f32x4 __attribute__((ext_vector_type(4)));

__device__ __forceinline__ float bf2f(u16 h) {
    union { unsigned u; float f; } x;
    x.u = ((unsigned)h) << 16;
    return x.f;
}
__device__ __forceinline__ u16 f2bf(float f) {
    union { float f; unsigned u; } x;
    x.f = f;
    unsigned r = x.u + 0x7fffu + ((x.u >> 16) & 1u);
    return (u16)(r >> 16);
}

// async global->LDS, 16B per lane; LDS dest is wave-uniform base + lane*16
__device__ __forceinline__ void gl_lds16(const u16* g, u16* l) {
    __builtin_amdgcn_global_load_lds((const __attribute__((address_space(1))) void*)g,
                                     (__attribute__((address_space(3))) void*)l, 16, 0, 0);
}

#define N1 8192
#define N2 2048
#define C2 256

// ---------------------------------------------------------------------------
// fused prep: w0/w1 fp32->bf16, xyz2 pack to float4(-2x,-2y,-2z,|p|^2),
// stats zero. (-2*x is EXACT in fp32, so sq = (psq+nsq) + dot(-2p,q) is
// bit-identical to the reference ((psq+nsq) - 2*dot).)
// ---------------------------------------------------------------------------
__global__ __launch_bounds__(256) void prep_misc(const float* __restrict__ w0,
                                                 const float* __restrict__ w1,
                                                 const float* __restrict__ xyz2,
                                                 u16* __restrict__ w0b,
                                                 u16* __restrict__ w1b,
                                                 float4* __restrict__ P2P,
                                                 float* __restrict__ stats) {
    int bid = blockIdx.x, tid = threadIdx.x;
    if (bid < 384) {
        int i = bid * 256 + tid;
        w0b[i] = f2bf(w0[i]);
    } else if (bid < 512) {
        int i = (bid - 384) * 256 + tid;
        w1b[i] = f2bf(w1[i]);
    } else if (bid < 576) {
        int i = (bid - 512) * 256 + tid;  // 16384 points
        float x = xyz2[i * 3 + 0], y = xyz2[i * 3 + 1], z = xyz2[i * 3 + 2];
        float nsq = __fadd_rn(__fadd_rn(__fmul_rn(x, x), __fmul_rn(y, y)), __fmul_rn(z, z));
        P2P[i] = make_float4(-2.0f * x, -2.0f * y, -2.0f * z, nsq);
    } else {
        for (int i = tid; i < 768; i += 256) stats[i] = 0.0f;
    }
}

// ---------------------------------------------------------------------------
// [B][C][N] fp32 -> [B][N][dst_stride] bf16 transpose (col offset col_off)
// ---------------------------------------------------------------------------
__global__ __launch_bounds__(256) void transpose_to_bf16(const float* __restrict__ src,
                                                         u16* __restrict__ dst,
                                                         int C, int N, int dst_stride,
                                                         int col_off) {
    __shared__ float tile[32][33];
    int b = blockIdx.z;
    int n0 = blockIdx.x * 32, c0 = blockIdx.y * 32;
    int tx = threadIdx.x & 31, ty = threadIdx.x >> 5;  // 32 x 8
    const float* s = src + (long)b * C * N;
#pragma unroll
    for (int i = 0; i < 4; i++) {
        int c = ty + i * 8;
        tile[c][tx] = s[(long)(c0 + c) * N + n0 + tx];
    }
    __syncthreads();
    u16* d = dst + (long)b * N * dst_stride;
#pragma unroll
    for (int i = 0; i < 4; i++) {
        int n = ty + i * 8;
        d[(long)(n0 + n) * dst_stride + col_off + c0 + tx] = f2bf(tile[tx][n]);
    }
}

// ---------------------------------------------------------------------------
// kNN(3) + inverse-distance interpolation, v5 (R5).
// R3 (LDS + nested-if cascade) = ~34 VALU/iter; R4 (scalar loads + ternary
// network) = ~41 (compiler inflated SGPR-resident path). v5: back to LDS
// staging (leaner codegen, proven) + min/max VALUE network (5 v_min/v_max,
// no masks) + 3 cmp + 5 cndmask for indices => ~21 VALU/iter target.
// Block 512 = 64 queries x 8 candidate partitions; 3 blocks/CU (46KB LDS),
// 24 waves/CU.
// ---------------------------------------------------------------------------
__global__ __launch_bounds__(512) void knn_interp(const float* __restrict__ xyz1,
                                                  const float4* __restrict__ P2P,  // [B][N2] packed
                                                  const u16* __restrict__ P2T,     // [B][N2][C2]
                                                  u16* __restrict__ X) {           // [B*N1][384]
    __shared__ float4 pts[N2];          // 32 KB packed (-2x,-2y,-2z,nsq)
    __shared__ float m_d[8][64][3];
    __shared__ int   m_i[8][64][3];
    __shared__ int   s_idx[64][3];
    __shared__ float s_w[64][3];
    int b = blockIdx.y;
    int n0 = blockIdx.x * 64;
    int tid = threadIdx.x;
    int ql = tid & 63;                                        // query lane
    int part = __builtin_amdgcn_readfirstlane(tid >> 6);      // wave id 0..7

    // stage packed candidates into LDS (values identical to R4-validated path)
    {
        const float4* src = P2P + (long)b * N2;
        for (int j = tid; j < N2; j += 512) pts[j] = src[j];
    }

    int n = n0 + ql;
    float px = xyz1[((long)b * N1 + n) * 3 + 0];
    float py = xyz1[((long)b * N1 + n) * 3 + 1];
    float pz = xyz1[((long)b * N1 + n) * 3 + 2];
    float psq = __fadd_rn(__fadd_rn(__fmul_rn(px, px), __fmul_rn(py, py)), __fmul_rn(pz, pz));
    __syncthreads();

    // scan this partition's 256 candidates (LDS broadcast reads, imm offsets)
    const float4* lp = &pts[part * (N2 / 8)];
    int jbase = part * (N2 / 8);
    float b0 = 1e30f, b1 = 1e30f, b2 = 1e30f;
    int i0 = 0, i1 = 0, i2 = 0;
#pragma unroll 8
    for (int jj = 0; jj < N2 / 8; jj++) {
        float4 p = lp[jj];
        float u = __fadd_rn(__fadd_rn(__fmul_rn(p.x, px), __fmul_rn(p.y, py)),
                            __fmul_rn(p.z, pz));
        float sq = __fadd_rn(__fadd_rn(psq, p.w), u);
        int j = jbase + jj;
        // index tracking: strict < keeps earlier index on ties (== reference)
        bool c0 = sq < b0, c1 = sq < b1, c2 = sq < b2;
        i2 = c2 ? (c1 ? i1 : j) : i2;
        i1 = c1 ? (c0 ? i0 : j) : i1;
        i0 = c0 ? j : i0;
        // value maintenance: pure min/max network (single-inst ops, no masks)
        float m1 = fmaxf(b0, sq);
        b0 = fminf(b0, sq);
        float m2 = fmaxf(b1, m1);
        b1 = fminf(b1, m1);
        b2 = fminf(b2, m2);
    }
    m_d[part][ql][0] = b0; m_d[part][ql][1] = b1; m_d[part][ql][2] = b2;
    m_i[part][ql][0] = i0; m_i[part][ql][1] = i1; m_i[part][ql][2] = i2;
    __syncthreads();

    // merge 8x3 partials -> top-3, lexicographic (sq, idx); partitions scan
    // disjoint ascending ranges so all 24 entries are distinct candidates.
    if (tid < 64) {
        float c0 = 1e30f, c1 = 1e30f, c2 = 1e30f;
        int a0 = 0x7fffffff, a1 = 0x7fffffff, a2 = 0x7fffffff;
#pragma unroll
        for (int pp2 = 0; pp2 < 8; pp2++) {
#pragma unroll
            for (int k = 0; k < 3; k++) {
                float d = m_d[pp2][tid][k];
                int ix = m_i[pp2][tid][k];
                if (d < c2 || (d == c2 && ix < a2)) {
                    if (d < c1 || (d == c1 && ix < a1)) {
                        c2 = c1; a2 = a1;
                        if (d < c0 || (d == c0 && ix < a0)) { c1 = c0; a1 = a0; c0 = d; a0 = ix; }
                        else                                { c1 = d; a1 = ix; }
                    } else { c2 = d; a2 = ix; }
                }
            }
        }
        // exact reference math for winners: d = sqrt(max(sq,0)), clamp 1e-10
        float e0 = sqrtf(fmaxf(c0, 0.0f));
        float e1 = sqrtf(fmaxf(c1, 0.0f));
        float e2 = sqrtf(fmaxf(c2, 0.0f));
        float kd0 = fmaxf(e0, 1e-10f), kd1 = fmaxf(e1, 1e-10f), kd2 = fmaxf(e2, 1e-10f);
        float w0 = __fdiv_rn(1.0f, kd0), w1 = __fdiv_rn(1.0f, kd1), w2 = __fdiv_rn(1.0f, kd2);
        float wsum = __fadd_rn(__fadd_rn(w0, w1), w2);
        s_idx[tid][0] = a0; s_idx[tid][1] = a1; s_idx[tid][2] = a2;
        s_w[tid][0] = __fdiv_rn(w0, wsum);
        s_w[tid][1] = __fdiv_rn(w1, wsum);
        s_w[tid][2] = __fdiv_rn(w2, wsum);
    }
    __syncthreads();

    // gather: wave w handles queries p = w, w+8, ...; lane l covers channels
    // [4l, 4l+4) as ushort4 (8 B/lane, coalesced 512 B/wave).
    int l = tid & 63;
    const u16* base = P2T + (long)b * N2 * C2;
    for (int p = part; p < 64; p += 8) {
        int j0 = s_idx[p][0], j1 = s_idx[p][1], j2 = s_idx[p][2];  // broadcast
        float f0 = s_w[p][0], f1 = s_w[p][1], f2 = s_w[p][2];
        ushort4 r0 = *(const ushort4*)&base[(long)j0 * C2 + l * 4];
        ushort4 r1 = *(const ushort4*)&base[(long)j1 * C2 + l * 4];
        ushort4 r2 = *(const ushort4*)&base[(long)j2 * C2 + l * 4];
        ushort4 o;
        o.x = f2bf(__fadd_rn(__fadd_rn(__fmul_rn(bf2f(r0.x), f0), __fmul_rn(bf2f(r1.x), f1)),
                             __fmul_rn(bf2f(r2.x), f2)));
        o.y = f2bf(__fadd_rn(__fadd_rn(__fmul_rn(bf2f(r0.y), f0), __fmul_rn(bf2f(r1.y), f1)),
                             __fmul_rn(bf2f(r2.y), f2)));
        o.z = f2bf(__fadd_rn(__fadd_rn(__fmul_rn(bf2f(r0.z), f0), __fmul_rn(bf2f(r1.z), f1)),
                             __fmul_rn(bf2f(r2.z), f2)));
        o.w = f2bf(__fadd_rn(__fadd_rn(__fmul_rn(bf2f(r0.w), f0), __fmul_rn(bf2f(r1.w), f1)),
                             __fmul_rn(bf2f(r2.w), f2)));
        *(ushort4*)&X[(long)(b * N1 + n0 + p) * 384 + 128 + l * 4] = o;
    }
}

// ---------------------------------------------------------------------------
// bf16 MFMA GEMM: Y[M][Ntot] = A[M][KDIM] * Bw[Ntot][KDIM]^T + bias (bf16 out)
// Block tile 128x128, 4 waves each 64x64 (4x4 of 16x16x32 MFMA).
// ASYNC=true (gemm0): global_load_lds width=16 staging, unpadded 128x32 LDS
//   tiles, XOR-swizzled global column pick so frag ds_read_b128 is 4-way
//   (not 8-way) bank-conflicted; no VGPR round-trip.
// ASYNC=false (gemm1): VGPR-roundtrip staging with fused input BN+ReLU,
//   padded stride-40 LDS.
// Epilogue accumulates per-output-channel sum / sumsq via atomics.
// ---------------------------------------------------------------------------
template <int KDIM, bool BN_IN, bool ASYNC>
__global__ __launch_bounds__(256) void gemm_bn(const u16* __restrict__ A,
                                               const u16* __restrict__ Bw,
                                               const float* __restrict__ bias,
                                               const float* __restrict__ g_in_sum,
                                               const float* __restrict__ g_in_ssq,
                                               const float* __restrict__ gamma_in,
                                               const float* __restrict__ beta_in,
                                               u16* __restrict__ Yout, int Ntot,
                                               float* __restrict__ g_out_sum,
                                               float* __restrict__ g_out_ssq) {
    constexpr int LD = ASYNC ? 32 : 40;  // u16 leading dim
    __shared__ __align__(16) u16 Al[128 * LD];
    __shared__ __align__(16) u16 Bl[128 * LD];
    __shared__ float s_stats[256];
    __shared__ float s_scale[BN_IN ? KDIM : 2];
    __shared__ float s_shift[BN_IN ? KDIM : 2];

    int tid = threadIdx.x;
    long s0 = (long)blockIdx.x * 128;
    int o0 = blockIdx.y * 128;

    s_stats[tid] = 0.0f;
    if constexpr (BN_IN) {
        for (int k = tid; k < KDIM; k += 256) {
            float mu = g_in_sum[k] * (1.0f / 65536.0f);
            float var = g_in_ssq[k] * (1.0f / 65536.0f) - mu * mu;
            float rs = rsqrtf(var + 1e-5f);
            float sc = gamma_in[k] * rs;
            s_scale[k] = sc;
            s_shift[k] = beta_in[k] - mu * sc;
        }
    }
    int wid = tid >> 6, lane = tid & 63;
    int wm = wid >> 1, wn = wid & 1;
    int q = lane >> 4, l16 = lane & 15;

    f32x4 acc[4][4];
#pragma unroll
    for (int mi = 0; mi < 4; mi++)
#pragma unroll
        for (int ni = 0; ni < 4; ni++) acc[mi][ni] = (f32x4){0.f, 0.f, 0.f, 0.f};

    // ASYNC staging precompute: issue c covers rows rbase+lane/4, col swizzled
    int rbase0 = wid * 32;            // issue 0 rows [rbase0, rbase0+16)
    int rsub = lane >> 2;             // 0..15
    int colsw = (((lane & 3) ^ (rsub & 3)) << 3);  // XOR-swizzled global col
    const u16* gA0 = A + (s0 + rbase0 + rsub) * KDIM + colsw;
    const u16* gA1 = gA0 + (long)16 * KDIM;
    const u16* gB0 = Bw + (long)(o0 + rbase0 + rsub) * KDIM + colsw;
    const u16* gB1 = gB0 + (long)16 * KDIM;
    u16* lA0 = &Al[rbase0 * 32];      // wave-uniform LDS bases
    u16* lA1 = &Al[(rbase0 + 16) * 32];
    u16* lB0 = &Bl[rbase0 * 32];
    u16* lB1 = &Bl[(rbase0 + 16) * 32];
    // frag-read column unswizzle (per-lane constant)
    int qA = ASYNC ? (q ^ (l16 & 3)) : q;

    __syncthreads();

    for (int kt = 0; kt < KDIM; kt += 32) {
        if constexpr (ASYNC) {
            gl_lds16(gA0 + kt, lA0);
            gl_lds16(gA1 + kt, lA1);
            gl_lds16(gB0 + kt, lB0);
            gl_lds16(gB1 + kt, lB1);
        } else {
#pragma unroll
            for (int cc = 0; cc < 2; cc++) {
                int ci = tid + cc * 256;
                int row = ci >> 2;
                int kc = (ci & 3) << 3;
                union { uint4 u; u16 h[8]; } va;
                va.u = *(const uint4*)(A + (s0 + row) * KDIM + kt + kc);
                if constexpr (BN_IN) {
#pragma unroll
                    for (int j = 0; j < 8; j++) {
                        float f = bf2f(va.h[j]);
                        f = fmaxf(fmaf(f, s_scale[kt + kc + j], s_shift[kt + kc + j]), 0.0f);
                        va.h[j] = f2bf(f);
                    }
                }
                *(uint4*)&Al[row * LD + kc] = va.u;
                *(uint4*)&Bl[row * LD + kc] = *(const uint4*)(Bw + (long)(o0 + row) * KDIM + kt + kc);
            }
        }
        __syncthreads();
        bf16x8 af[4], bfr[4];
#pragma unroll
        for (int mi = 0; mi < 4; mi++)
            af[mi] = *(const bf16x8*)&Al[(wm * 64 + mi * 16 + l16) * LD + qA * 8];
#pragma unroll
        for (int ni = 0; ni < 4; ni++)
            bfr[ni] = *(const bf16x8*)&Bl[(wn * 64 + ni * 16 + l16) * LD + qA * 8];
#pragma unroll
        for (int mi = 0; mi < 4; mi++)
#pragma unroll
            for (int ni = 0; ni < 4; ni++)
                acc[mi][ni] = __builtin_amdgcn_mfma_f32_16x16x32_bf16(af[mi], bfr[ni],
                                                                      acc[mi][ni], 0, 0, 0);
        __syncthreads();
    }

    // epilogue: bias add, store, per-channel sum/sumsq
#pragma unroll
    for (int ni = 0; ni < 4; ni++) {
        int coll = wn * 64 + ni * 16 + l16;
        int col = o0 + coll;
        float bz = bias[col];
        float s1 = 0.0f, s2 = 0.0f;
#pragma unroll
        for (int mi = 0; mi < 4; mi++) {
#pragma unroll
            for (int r = 0; r < 4; r++) {
                float v = acc[mi][ni][r] + bz;
                s1 += v;
                s2 += v * v;
                long row = s0 + wm * 64 + mi * 16 + q * 4 + r;
                Yout[row * Ntot + col] = f2bf(v);
            }
        }
        s1 += __shfl_xor(s1, 16, 64);
        s1 += __shfl_xor(s1, 32, 64);
        s2 += __shfl_xor(s2, 16, 64);
        s2 += __shfl_xor(s2, 32, 64);
        if (q == 0) {
            atomicAdd(&s_stats[coll], s1);
            atomicAdd(&s_stats[128 + coll], s2);
        }
    }
    __syncthreads();
    if (tid < 128) {
        atomicAdd(&g_out_sum[o0 + tid], s_stats[tid]);
        atomicAdd(&g_out_ssq[o0 + tid], s_stats[128 + tid]);
    }
}

// ---------------------------------------------------------------------------
// final BN+ReLU + transpose to [B][128][N1] fp32 (Y1 bf16, 16B reads)
// ---------------------------------------------------------------------------
__global__ __launch_bounds__(256) void finalize_k(const u16* __restrict__ Y1,  // [M][128] bf16
                                                  const float* __restrict__ g_sum,
                                                  const float* __restrict__ g_ssq,
                                                  const float* __restrict__ gamma,
                                                  const float* __restrict__ beta,
                                                  float* __restrict__ out) {
    __shared__ float s_scale[128], s_shift[128];
    int tid = threadIdx.x;
    if (tid < 128) {
        float mu = g_sum[tid] * (1.0f / 65536.0f);
        float var = g_ssq[tid] * (1.0f / 65536.0f) - mu * mu;
        float rs = rsqrtf(var + 1e-5f);
        float sc = gamma[tid] * rs;
        s_scale[tid] = sc;
        s_shift[tid] = beta[tid] - mu * sc;
    }
    __syncthreads();
    long s = (long)blockIdx.x * 256 + tid;
    int b = (int)(s >> 13);
    int n = (int)(s & 8191);
    const u16* yrow = Y1 + s * 128;
    float* obase = out + (long)b * 128 * 8192 + n;
#pragma unroll
    for (int oc = 0; oc < 128; oc += 8) {
        union { uint4 u; u16 h[8]; } va;
        va.u = *(const uint4*)&yrow[oc];
#pragma unroll
        for (int k = 0; k < 8; k++) {
            int o = oc + k;
            float v = fmaxf(fmaf(bf2f(va.h[k]), s_scale[o], s_shift[o]), 0.0f);
            obase[(long)o * 8192] = v;
        }
    }
}

// ---------------------------------------------------------------------------
// launch
// ---------------------------------------------------------------------------
extern "C" void kernel_launch(void* const* d_in, const int* in_sizes, int n_in,
                              void* d_out, int out_size, void* d_ws, size_t ws_size,
                              hipStream_t stream) {
    const float* xyz1    = (const float*)d_in[0];
    const float* xyz2    = (const float*)d_in[1];
    const float* points1 = (const float*)d_in[2];
    const float* points2 = (const float*)d_in[3];
    const float* w0 = (const float*)d_in[4];
    const float* b0 = (const float*)d_in[5];
    const float* gamma0 = (const float*)d_in[6];
    const float* beta0 = (const float*)d_in[7];
    const float* w1 = (const float*)d_in[8];
    const float* b1 = (const float*)d_in[9];
    const float* gamma1 = (const float*)d_in[10];
    const float* beta1 = (const float*)d_in[11];
    float* out = (float*)d_out;

    char* ws = (char*)d_ws;
    // ws layout (all 256B aligned)
    u16* X      = (u16*)(ws + 0);            // 65536 x 384 bf16 = 50,331,648
    u16* P2T    = (u16*)(ws + 50331648);     // 8 x 2048 x 256 bf16 = 8,388,608
    u16* w0b    = (u16*)(ws + 58720256);     // 256 x 384 bf16 = 196,608
    u16* w1b    = (u16*)(ws + 58916864);     // 128 x 256 bf16 = 65,536
    u16* Y0     = (u16*)(ws + 58982400);     // 65536 x 256 bf16 = 33,554,432
    float4* P2P = (float4*)(ws + 92536832);  // 16384 x 16 = 262,144
    u16* Y1b    = (u16*)(ws + 92798976);     // 65536 x 128 bf16 = 16,777,216
    float* stats = (float*)(ws + 126091264); // 768 floats
    if (ws_size < 126094336) return;  // insufficient scratch -> visible failure
    float* gsum0 = stats;
    float* gss0  = stats + 256;
    float* gsum1 = stats + 512;
    float* gss1  = stats + 640;

    prep_misc<<<577, 256, 0, stream>>>(w0, w1, xyz2, w0b, w1b, P2P, stats);
    transpose_to_bf16<<<dim3(256, 4, 8), 256, 0, stream>>>(points1, X, 128, 8192, 384, 0);
    transpose_to_bf16<<<dim3(64, 8, 8), 256, 0, stream>>>(points2, P2T, 256, 2048, 256, 0);
    knn_interp<<<dim3(128, 8), 512, 0, stream>>>(xyz1, P2P, P2T, X);
    gemm_bn<384, false, true><<<dim3(512, 2), 256, 0, stream>>>(
        X, w0b, b0, nullptr, nullptr, nullptr, nullptr, Y0, 256, gsum0, gss0);
    gemm_bn<256, true, false><<<dim3(512, 1), 256, 0, stream>>>(
        Y0, w1b, b1, gsum0, gss0, gamma0, beta0, Y1b, 128, gsum1, gss1);
    finalize_k<<<256, 256, 0, stream>>>(Y1b, gsum1, gss1, gamma1, beta1, out);
}